// Round 18
// baseline (4348.686 us; speedup 1.0000x reference)
//
#include <hip/hip_runtime.h>
#include <math.h>

// Problem constants: T=131072, D_IN=1024, NE=64, top_k=2
constexpr int T_TOKENS = 131072;
constexpr int D        = 1024;
constexpr float EPS_GAP = 1e-3f;   // flag threshold (bf16-split err ~1e-5 RMS)

typedef __attribute__((ext_vector_type(8))) short bf16x8;
typedef __attribute__((ext_vector_type(4))) float f32x4;
typedef __bf16 bf16v8 __attribute__((ext_vector_type(8)));
typedef float  f32v8  __attribute__((ext_vector_type(8)));

// split 8 fp32 into two bf16 planes (RNE): f ~= p0 + p1
__device__ __forceinline__ void split2(const float4 lo, const float4 hi,
                                       bf16x8& p0, bf16x8& p1) {
    f32v8 f = {lo.x, lo.y, lo.z, lo.w, hi.x, hi.y, hi.z, hi.w};
    bf16v8 h0 = __builtin_convertvector(f, bf16v8);
    f32v8 back = __builtin_convertvector(h0, f32v8);
    bf16v8 h1 = __builtin_convertvector(f - back, bf16v8);
    p0 = __builtin_bit_cast(bf16x8, h0);
    p1 = __builtin_bit_cast(bf16x8, h1);
}

// ---- Kernel 0: pre-split W into fragment-layout bf16 planes (256 KB) ------
// wpl[((g*4+c)*2+p)*64 + l] = plane_p( W[c*16 + (l&15)][g*32 + (l>>4)*8 .. +8] )
__global__ void prep_w(const float* __restrict__ W, bf16x8* __restrict__ wpl) {
    const int g = blockIdx.x;          // 0..31 (K window of 32)
    const int c = threadIdx.x >> 6;    // 0..3
    const int l = threadIdx.x & 63;
    const int e  = c * 16 + (l & 15);
    const int k0 = g * 32 + (l >> 4) * 8;
    const float4 lo = *(const float4*)(W + (long)e * D + k0);
    const float4 hi = *(const float4*)(W + (long)e * D + k0 + 4);
    bf16x8 p0, p1; split2(lo, hi, p0, p1);
    const int base = ((g * 4 + c) * 2) * 64 + l;
    wpl[base]      = p0;
    wpl[base + 64] = p1;
}

// ---- Kernel 1: dual-stream LDS pipeline, W via lgkmcnt, A via counted vmcnt
// 512 blocks x 128 thr (2 waves); block = 4 tiles x 64 tokens; wave = 32 tok.
// Per chunk (KSTEP=128): A wave-private 16KB (16 x 1KB gload_lds, 512B runs,
// XOR-swizzled source); W shared 32KB from L2-hot wpl (32 x 1KB gload_lds).
// Compute reads BOTH from LDS -> W waits are lgkmcnt, never draining the
// A-prefetch vmcnt stream. One raw s_barrier + one vmcnt(0) per chunk.
__global__ __launch_bounds__(128)
void router_mfma(const float* __restrict__ x, const bf16x8* __restrict__ wpl,
                 float* __restrict__ out, unsigned* __restrict__ wcnt,
                 unsigned* __restrict__ wlist, unsigned cap)
{
    // layout: A[wv][buf] at wv*32768 + buf*16384 (16KB each)
    //         W[buf]     at 65536 + buf*32768   (32KB each)   total 128KB
    __shared__ __align__(16) char lds[131072];

    const int tid = threadIdx.x;
    const int wv  = tid >> 6;
    const int l   = tid & 63;
    const int lg  = l >> 4;       // k-octet
    const int lr  = l & 15;       // token row in tile / expert in ctile
    const int swz = (lr & 7) << 4;
    const long blk0 = (long)blockIdx.x * 256;   // 4 tiles x 64 tokens
    const char* xb  = (const char*)x;
    const char* wbg = (const char*)wpl;

    f32x4 acc[2][4];
#pragma unroll
    for (int a = 0; a < 2; ++a)
#pragma unroll
        for (int c = 0; c < 4; ++c) acc[a][c] = f32x4{0.f, 0.f, 0.f, 0.f};

#define STAGE(C, BUF)                                                          \
    {                                                                          \
        const long rowb = blk0 + ((C) >> 3) * 64 + wv * 32;                    \
        const int  kb   = (C) & 7;                                             \
        _Pragma("unroll")                                                      \
        for (int i = 0; i < 16; ++i) {                                         \
            const int rr = 2 * i + (l >> 5);                                   \
            const char* src = xb + (rowb + rr) * 4096L + kb * 512              \
                              + (((l & 31) * 16) ^ ((rr & 7) << 4));           \
            char* dst = &lds[wv * 32768 + (BUF) * 16384 + i * 1024];           \
            __builtin_amdgcn_global_load_lds(                                  \
                (const __attribute__((address_space(1))) void*)src,            \
                (__attribute__((address_space(3))) void*)dst, 16, 0, 0);       \
        }                                                                      \
        _Pragma("unroll")                                                      \
        for (int j = 0; j < 16; ++j) {                                         \
            const int idx = wv * 16 + j;                                       \
            const char* src = wbg + ((long)kb * 32 + idx) * 1024 + l * 16;     \
            char* dst = &lds[65536 + (BUF) * 32768 + idx * 1024];              \
            __builtin_amdgcn_global_load_lds(                                  \
                (const __attribute__((address_space(1))) void*)src,            \
                (__attribute__((address_space(3))) void*)dst, 16, 0, 0);       \
        }                                                                      \
    }

#define SUBSTEP(SUB, BUF)                                                      \
    {                                                                          \
        bf16x8 wf[8];                                                          \
        _Pragma("unroll")                                                      \
        for (int q = 0; q < 8; ++q)                                            \
            wf[q] = *(const bf16x8*)&lds[65536 + (BUF) * 32768                 \
                                         + ((SUB) * 8 + q) * 1024 + l * 16];   \
        _Pragma("unroll")                                                      \
        for (int a = 0; a < 2; ++a) {                                          \
            const char* ab = &lds[wv * 32768 + (BUF) * 16384                   \
                                  + (a * 16 + lr) * 512];                      \
            const int c0 = (SUB) * 128 + lg * 32;                              \
            const float4 lo = *(const float4*)(ab + (c0 ^ swz));               \
            const float4 hi = *(const float4*)(ab + ((c0 + 16) ^ swz));        \
            bf16x8 a0, a1;                                                     \
            split2(lo, hi, a0, a1);                                            \
            _Pragma("unroll")                                                  \
            for (int c = 0; c < 4; ++c) {                                      \
                acc[a][c] = __builtin_amdgcn_mfma_f32_16x16x32_bf16(a0, wf[c*2+0], acc[a][c], 0, 0, 0); \
                acc[a][c] = __builtin_amdgcn_mfma_f32_16x16x32_bf16(a1, wf[c*2+0], acc[a][c], 0, 0, 0); \
                acc[a][c] = __builtin_amdgcn_mfma_f32_16x16x32_bf16(a0, wf[c*2+1], acc[a][c], 0, 0, 0); \
            }                                                                  \
        }                                                                      \
    }

    STAGE(0, 0);

#pragma unroll 1
    for (int it = 0; it < 4; ++it) {
#pragma unroll 1
        for (int k8 = 0; k8 < 8; ++k8) {
            const int c   = it * 8 + k8;
            const int buf = c & 1;
            // stage(c) is the only vmcnt traffic in flight -> this wait is
            // exactly the data dependency, issued one compute-period after.
            asm volatile("s_waitcnt vmcnt(0)" ::: "memory");
            __builtin_amdgcn_sched_barrier(0);
            __builtin_amdgcn_s_barrier();     // both waves' stages visible
            __builtin_amdgcn_sched_barrier(0);
            if (c + 1 < 32) { STAGE(c + 1, buf ^ 1) }
            SUBSTEP(0, buf)
            SUBSTEP(1, buf)
            SUBSTEP(2, buf)
            SUBSTEP(3, buf)
        }

        // ---- tile epilogue: top-3 per token, provisional write + gap-flag --
        const long t0w = blk0 + it * 64 + wv * 32;
#pragma unroll
        for (int a = 0; a < 2; ++a)
#pragma unroll
        for (int r = 0; r < 4; ++r) {
            float v1 = acc[a][0][r]; int i1 = lr;
            float v2 = -INFINITY;    int i2 = 1 << 20;
            float v3 = -INFINITY;
#pragma unroll
            for (int c = 1; c < 4; ++c) {
                const float v = acc[a][c][r]; const int e = lr + 16 * c;
                if (v > v1)      { v3 = v2; v2 = v1; i2 = i1; v1 = v; i1 = e; }
                else if (v > v2) { v3 = v2; v2 = v;  i2 = e; }
                else if (v > v3) { v3 = v; }
            }
#pragma unroll
            for (int m = 8; m >= 1; m >>= 1) {
                const float ov1 = __shfl_xor(v1, m);
                const int   oi1 = __shfl_xor(i1, m);
                const float ov2 = __shfl_xor(v2, m);
                const int   oi2 = __shfl_xor(i2, m);
                const float ov3 = __shfl_xor(v3, m);
                const bool tv = v1 >= ov1;
                const float x2 = tv ? v2 : ov2, x3 = tv ? v3 : ov3;
                const float y1 = tv ? ov1 : v1, y2 = tv ? ov2 : v2;
                const float nv3 = (x2 >= y1) ? fmaxf(x3, y1) : fmaxf(x2, y2);
                const bool aw = (ov1 > v1) || (ov1 == v1 && oi1 < i1);
                const float nv1 = aw ? ov1 : v1; const int ni1 = aw ? oi1 : i1;
                const float c1v = aw ? v1  : ov1; const int c1i = aw ? i1  : oi1;
                const float c2v = aw ? ov2 : v2;  const int c2i = aw ? oi2 : i2;
                const bool bw = (c1v > c2v) || (c1v == c2v && c1i < c2i);
                v1 = nv1; i1 = ni1;
                v2 = bw ? c1v : c2v; i2 = bw ? c1i : c2i;
                v3 = nv3;
            }
            if (lr == 0) {
                const long t = t0w + a * 16 + lg * 4 + r;
                const float e  = expf(v2 - v1);
                const float dn = 1.0f + e;
                out[t * 2 + 0] = (float)i1;
                out[t * 2 + 1] = (float)i2;
                out[(long)T_TOKENS * 2 + t * 2 + 0] = 1.0f / dn;
                out[(long)T_TOKENS * 2 + t * 2 + 1] = e / dn;
                if (v1 - v2 < EPS_GAP || v2 - v3 < EPS_GAP) {
                    const unsigned p = atomicAdd(wcnt, 1u);
                    if (p < cap) wlist[p] = (unsigned)t;
                }
            }
            acc[a][0] = f32x4{0.f, 0.f, 0.f, 0.f};
            acc[a][1] = f32x4{0.f, 0.f, 0.f, 0.f};
            acc[a][2] = f32x4{0.f, 0.f, 0.f, 0.f};
            acc[a][3] = f32x4{0.f, 0.f, 0.f, 0.f};
        }
    }
#undef SUBSTEP
#undef STAGE
}

// ---- Kernel 2: exact-chain fixup, 4 waves/token (one per OpenBLAS panel) --
// Exact OpenBLAS-SKYLAKEX chain (verified R7+): panels 320/320/192/192,
// ascending-k fp32 FMA chain per panel, sequential rounded folds.
__global__ __launch_bounds__(256)
void router_fixup(const float* __restrict__ x, const float* __restrict__ W,
                  float* __restrict__ out, const unsigned* __restrict__ wcnt,
                  const unsigned* __restrict__ wlist, unsigned cap)
{
    __shared__ float ps[4][64];
    unsigned cnt = wcnt[0]; if (cnt > cap) cnt = cap;
    const int wv = threadIdx.x >> 6;   // panel id
    const int l  = threadIdx.x & 63;   // expert
    const int kb = (wv == 0) ? 0 : (wv == 1) ? 320 : (wv == 2) ? 640 : 832;
    const int ke = (wv == 0) ? 320 : (wv == 1) ? 640 : (wv == 2) ? 832 : 1024;

    for (unsigned it = blockIdx.x; it < cnt; it += gridDim.x) {
        const long t = (long)wlist[it];
        const float* xr = x + t * (long)D;
        const float* wr = W + (long)l * D;
        float accP = 0.f;
#pragma unroll 4
        for (int k = kb; k < ke; k += 4) {
            const float4 xv = *(const float4*)(xr + k);
            const float4 wvv = *(const float4*)(wr + k);
            accP = fmaf(xv.x, wvv.x, accP);
            accP = fmaf(xv.y, wvv.y, accP);
            accP = fmaf(xv.z, wvv.z, accP);
            accP = fmaf(xv.w, wvv.w, accP);
        }
        ps[wv][l] = accP;
        __syncthreads();
        if (wv == 0) {
            const float accT = __fadd_rn(__fadd_rn(__fadd_rn(ps[0][l], ps[1][l]), ps[2][l]), ps[3][l]);
            float v1 = accT; int i1 = l;
            float v2 = -INFINITY; int i2 = 1 << 20;
#pragma unroll
            for (int m = 32; m >= 1; m >>= 1) {
                const float ov1 = __shfl_xor(v1, m);
                const int   oi1 = __shfl_xor(i1, m);
                const float ov2 = __shfl_xor(v2, m);
                const int   oi2 = __shfl_xor(i2, m);
                const bool aw = (ov1 > v1) || (ov1 == v1 && oi1 < i1);
                const float nv1 = aw ? ov1 : v1; const int ni1 = aw ? oi1 : i1;
                const float c1v = aw ? v1  : ov1; const int c1i = aw ? i1  : oi1;
                const float c2v = aw ? ov2 : v2;  const int c2i = aw ? oi2 : i2;
                const bool bw = (c1v > c2v) || (c1v == c2v && c1i < c2i);
                v1 = nv1; i1 = ni1;
                v2 = bw ? c1v : c2v; i2 = bw ? c1i : c2i;
            }
            if (l == 0) {
                const float e  = expf(v2 - v1);
                const float dn = 1.0f + e;
                out[t * 2 + 0] = (float)i1;
                out[t * 2 + 1] = (float)i2;
                out[(long)T_TOKENS * 2 + t * 2 + 0] = 1.0f / dn;
                out[(long)T_TOKENS * 2 + t * 2 + 1] = e / dn;
            }
        }
        __syncthreads();
    }
}

extern "C" void kernel_launch(void* const* d_in, const int* in_sizes, int n_in,
                              void* d_out, int out_size, void* d_ws, size_t ws_size,
                              hipStream_t stream) {
    const float* x = (const float*)d_in[0];
    const float* W = (const float*)d_in[1];
    float* out = (float*)d_out;

    // workspace layout: [0,64) wcnt | [1024, 1024+256K) W frag planes | wlist
    unsigned* wcnt  = (unsigned*)d_ws;
    bf16x8*   wpl   = (bf16x8*)((char*)d_ws + 1024);
    unsigned* wlist = (unsigned*)((char*)d_ws + 1024 + 262144);
    size_t rem = (ws_size - 1024 - 262144) / 4;
    unsigned cap = (unsigned)(rem > (1u << 22) ? (1u << 22) : rem);

    (void)hipMemsetAsync(d_ws, 0, 64, stream);
    prep_w<<<dim3(32), dim3(256), 0, stream>>>(W, wpl);
    router_mfma<<<dim3(T_TOKENS / 256), dim3(128), 0, stream>>>(x, wpl, out, wcnt, wlist, cap);
    router_fixup<<<dim3(512), dim3(256), 0, stream>>>(x, W, out, wcnt, wlist, cap);
}

// Round 19
// 196.392 us; speedup vs baseline: 22.1428x; 22.1428x over previous
//
#include <hip/hip_runtime.h>
#include <math.h>

// Problem constants: T=131072, D_IN=1024, NE=64, top_k=2
constexpr int T_TOKENS = 131072;
constexpr int D        = 1024;
constexpr float EPS_GAP = 1e-3f;   // flag threshold (bf16-split err ~1e-5 RMS)

typedef __attribute__((ext_vector_type(8))) short bf16x8;
typedef __attribute__((ext_vector_type(4))) float f32x4;
typedef __bf16 bf16v8 __attribute__((ext_vector_type(8)));
typedef float  f32v8  __attribute__((ext_vector_type(8)));

// split 8 fp32 into two bf16 planes (RNE): f ~= p0 + p1
__device__ __forceinline__ void split2(const float4 lo, const float4 hi,
                                       bf16x8& p0, bf16x8& p1) {
    f32v8 f = {lo.x, lo.y, lo.z, lo.w, hi.x, hi.y, hi.z, hi.w};
    bf16v8 h0 = __builtin_convertvector(f, bf16v8);
    f32v8 back = __builtin_convertvector(h0, f32v8);
    bf16v8 h1 = __builtin_convertvector(f - back, bf16v8);
    p0 = __builtin_bit_cast(bf16x8, h0);
    p1 = __builtin_bit_cast(bf16x8, h1);
}

// ---- Kernel 0: pre-split W into fragment-layout bf16 planes (256 KB) ------
// wpl[g*512 + (c*2+p)*64 + l] = plane_p( W[c*16 + (l&15)][g*32 + (l>>4)*8 .. +8] )
__global__ void prep_w(const float* __restrict__ W, bf16x8* __restrict__ wpl) {
    const int g = blockIdx.x;          // 0..31 (K window of 32)
    const int c = threadIdx.x >> 6;    // 0..3
    const int l = threadIdx.x & 63;
    const int e  = c * 16 + (l & 15);
    const int k0 = g * 32 + (l >> 4) * 8;
    const float4 lo = *(const float4*)(W + (long)e * D + k0);
    const float4 hi = *(const float4*)(W + (long)e * D + k0 + 4);
    bf16x8 p0, p1; split2(lo, hi, p0, p1);
    const int base = ((g * 4 + c) * 2) * 64 + l;
    wpl[base]      = p0;
    wpl[base + 64] = p1;
}

// ---- Kernel 1: zero-barrier MFMA router, KSTEP=32, 16 waves/CU ------------
// 1024 blocks x 256 thr (4 independent waves; NO __syncthreads).
// Wave = 32 tokens x 64 experts. A: 128B-per-row chunks staged via
// global_load_lds into wave-private double buffers (2 x 4KB/wave; 32KB/block
// -> 4 blocks/CU -> 16 waves/CU). Sync = counted s_waitcnt vmcnt(12) only.
// W: prep_w fragment planes in registers (8 x 16B/chunk, L1-hot), issued
// before the stage so in-order retirement never drains the prefetch.
__global__ __launch_bounds__(256, 4)
void router_mfma(const float* __restrict__ x, const bf16x8* __restrict__ wpl,
                 float* __restrict__ out, unsigned* __restrict__ wcnt,
                 unsigned* __restrict__ wlist, unsigned cap)
{
    __shared__ __align__(16) char Xs[4][2][4096];   // [wave][buf][32 rows x 128B]

    const int tid = threadIdx.x;
    const int wv  = tid >> 6;
    const int l   = tid & 63;
    const int lg  = l >> 4;       // k-octet
    const int lr  = l & 15;       // token row in tile / expert in ctile
    const long t0 = (long)blockIdx.x * 128 + wv * 32;
    const int swz = (lr & 7) << 4;
    const char* xb = (const char*)x;

    f32x4 acc[2][4];
#pragma unroll
    for (int a = 0; a < 2; ++a)
#pragma unroll
        for (int c = 0; c < 4; ++c) acc[a][c] = f32x4{0.f, 0.f, 0.f, 0.f};

    // staging: instr i covers rows 8i..8i+7; lane l -> row 8i+(l>>3),
    // byte (l&7)*16 of the row's 128B window, XOR-preswizzled source.
#define STAGE(S, BUF)                                                          \
    {                                                                          \
        _Pragma("unroll")                                                      \
        for (int i = 0; i < 4; ++i) {                                          \
            const int rr = 8 * i + (l >> 3);                                   \
            const char* src = xb + (t0 + rr) * 4096L + (S) * 128               \
                              + (((l & 7) * 16) ^ ((rr & 7) << 4));            \
            char* dst = &Xs[wv][BUF][i * 1024];                                \
            __builtin_amdgcn_global_load_lds(                                  \
                (const __attribute__((address_space(1))) void*)src,            \
                (__attribute__((address_space(3))) void*)dst, 16, 0, 0);       \
        }                                                                      \
    }

    STAGE(0, 0);

#pragma unroll 1
    for (int s = 0; s < 32; ++s) {
        const int buf = s & 1;
        // 1. W fragments for k-window s (L1-hot), issued first
        bf16x8 w[8];
#pragma unroll
        for (int q = 0; q < 8; ++q)
            w[q] = wpl[(size_t)s * 512 + q * 64 + l];
        // 2. issue next chunk's staging (clamped redundant on last iter)
        const int sn = (s + 1 < 32) ? s + 1 : 31;
        if (buf) { STAGE(sn, 0) } else { STAGE(sn, 1) }
        // 3. counted wait: outstanding = stage(s):4 + W:8 + stage(next):4
        //    -> vmcnt(12) retires exactly stage(s)
        asm volatile("s_waitcnt vmcnt(12)" ::: "memory");
        __builtin_amdgcn_sched_barrier(0);
        // 4. compute chunk s (32 k) for both 16-row tiles
        const char* ab = &Xs[wv][buf][0];
#pragma unroll
        for (int a = 0; a < 2; ++a) {
            const char* rowp = ab + (a * 16 + lr) * 128;
            const int c0 = lg * 32;
            const float4 lo = *(const float4*)(rowp + (c0 ^ swz));
            const float4 hi = *(const float4*)(rowp + ((c0 + 16) ^ swz));
            bf16x8 a0, a1;
            split2(lo, hi, a0, a1);
#pragma unroll
            for (int c = 0; c < 4; ++c) {
                acc[a][c] = __builtin_amdgcn_mfma_f32_16x16x32_bf16(a0, w[c*2+0], acc[a][c], 0, 0, 0);
                acc[a][c] = __builtin_amdgcn_mfma_f32_16x16x32_bf16(a1, w[c*2+0], acc[a][c], 0, 0, 0);
                acc[a][c] = __builtin_amdgcn_mfma_f32_16x16x32_bf16(a0, w[c*2+1], acc[a][c], 0, 0, 0);
            }
        }
    }
#undef STAGE

    // ---- epilogue: top-3 per token, provisional write + gap-flag ----
    // C/D: col = lane&15 (expert in ctile), row = (lane>>4)*4 + reg (token)
#pragma unroll
    for (int a = 0; a < 2; ++a)
#pragma unroll
    for (int r = 0; r < 4; ++r) {
        float v1 = acc[a][0][r]; int i1 = lr;
        float v2 = -INFINITY;    int i2 = 1 << 20;
        float v3 = -INFINITY;
#pragma unroll
        for (int c = 1; c < 4; ++c) {
            const float v = acc[a][c][r]; const int e = lr + 16 * c;
            if (v > v1)      { v3 = v2; v2 = v1; i2 = i1; v1 = v; i1 = e; }
            else if (v > v2) { v3 = v2; v2 = v;  i2 = e; }
            else if (v > v3) { v3 = v; }
        }
#pragma unroll
        for (int m = 8; m >= 1; m >>= 1) {
            const float ov1 = __shfl_xor(v1, m);
            const int   oi1 = __shfl_xor(i1, m);
            const float ov2 = __shfl_xor(v2, m);
            const int   oi2 = __shfl_xor(i2, m);
            const float ov3 = __shfl_xor(v3, m);
            const bool tv = v1 >= ov1;
            const float x2 = tv ? v2 : ov2, x3 = tv ? v3 : ov3;
            const float y1 = tv ? ov1 : v1, y2 = tv ? ov2 : v2;
            const float nv3 = (x2 >= y1) ? fmaxf(x3, y1) : fmaxf(x2, y2);
            const bool aw = (ov1 > v1) || (ov1 == v1 && oi1 < i1);
            const float nv1 = aw ? ov1 : v1; const int ni1 = aw ? oi1 : i1;
            const float c1v = aw ? v1  : ov1; const int c1i = aw ? i1  : oi1;
            const float c2v = aw ? ov2 : v2;  const int c2i = aw ? oi2 : i2;
            const bool bw = (c1v > c2v) || (c1v == c2v && c1i < c2i);
            v1 = nv1; i1 = ni1;
            v2 = bw ? c1v : c2v; i2 = bw ? c1i : c2i;
            v3 = nv3;
        }
        if (lr == 0) {
            const long t = t0 + a * 16 + lg * 4 + r;
            const float e  = expf(v2 - v1);
            const float dn = 1.0f + e;
            out[t * 2 + 0] = (float)i1;
            out[t * 2 + 1] = (float)i2;
            out[(long)T_TOKENS * 2 + t * 2 + 0] = 1.0f / dn;
            out[(long)T_TOKENS * 2 + t * 2 + 1] = e / dn;
            if (v1 - v2 < EPS_GAP || v2 - v3 < EPS_GAP) {
                const unsigned p = atomicAdd(wcnt, 1u);
                if (p < cap) wlist[p] = (unsigned)t;
            }
        }
    }
}

// ---- Kernel 2: exact-chain fixup, 4 waves/token (one per OpenBLAS panel) --
// Exact OpenBLAS-SKYLAKEX chain (verified R7+): panels 320/320/192/192,
// ascending-k fp32 FMA chain per panel, sequential rounded folds.
__global__ __launch_bounds__(256)
void router_fixup(const float* __restrict__ x, const float* __restrict__ W,
                  float* __restrict__ out, const unsigned* __restrict__ wcnt,
                  const unsigned* __restrict__ wlist, unsigned cap)
{
    __shared__ float ps[4][64];
    unsigned cnt = wcnt[0]; if (cnt > cap) cnt = cap;
    const int wv = threadIdx.x >> 6;   // panel id
    const int l  = threadIdx.x & 63;   // expert
    const int kb = (wv == 0) ? 0 : (wv == 1) ? 320 : (wv == 2) ? 640 : 832;
    const int ke = (wv == 0) ? 320 : (wv == 1) ? 640 : (wv == 2) ? 832 : 1024;

    for (unsigned it = blockIdx.x; it < cnt; it += gridDim.x) {
        const long t = (long)wlist[it];
        const float* xr = x + t * (long)D;
        const float* wr = W + (long)l * D;
        float accP = 0.f;
#pragma unroll 4
        for (int k = kb; k < ke; k += 4) {
            const float4 xv = *(const float4*)(xr + k);
            const float4 wvv = *(const float4*)(wr + k);
            accP = fmaf(xv.x, wvv.x, accP);
            accP = fmaf(xv.y, wvv.y, accP);
            accP = fmaf(xv.z, wvv.z, accP);
            accP = fmaf(xv.w, wvv.w, accP);
        }
        ps[wv][l] = accP;
        __syncthreads();
        if (wv == 0) {
            const float accT = __fadd_rn(__fadd_rn(__fadd_rn(ps[0][l], ps[1][l]), ps[2][l]), ps[3][l]);
            float v1 = accT; int i1 = l;
            float v2 = -INFINITY; int i2 = 1 << 20;
#pragma unroll
            for (int m = 32; m >= 1; m >>= 1) {
                const float ov1 = __shfl_xor(v1, m);
                const int   oi1 = __shfl_xor(i1, m);
                const float ov2 = __shfl_xor(v2, m);
                const int   oi2 = __shfl_xor(i2, m);
                const bool aw = (ov1 > v1) || (ov1 == v1 && oi1 < i1);
                const float nv1 = aw ? ov1 : v1; const int ni1 = aw ? oi1 : i1;
                const float c1v = aw ? v1  : ov1; const int c1i = aw ? i1  : oi1;
                const float c2v = aw ? ov2 : v2;  const int c2i = aw ? oi2 : i2;
                const bool bw = (c1v > c2v) || (c1v == c2v && c1i < c2i);
                v1 = nv1; i1 = ni1;
                v2 = bw ? c1v : c2v; i2 = bw ? c1i : c2i;
            }
            if (l == 0) {
                const float e  = expf(v2 - v1);
                const float dn = 1.0f + e;
                out[t * 2 + 0] = (float)i1;
                out[t * 2 + 1] = (float)i2;
                out[(long)T_TOKENS * 2 + t * 2 + 0] = 1.0f / dn;
                out[(long)T_TOKENS * 2 + t * 2 + 1] = e / dn;
            }
        }
        __syncthreads();
    }
}

extern "C" void kernel_launch(void* const* d_in, const int* in_sizes, int n_in,
                              void* d_out, int out_size, void* d_ws, size_t ws_size,
                              hipStream_t stream) {
    const float* x = (const float*)d_in[0];
    const float* W = (const float*)d_in[1];
    float* out = (float*)d_out;

    // workspace layout: [0,64) wcnt | [1024, 1024+256K) W frag planes | wlist
    unsigned* wcnt  = (unsigned*)d_ws;
    bf16x8*   wpl   = (bf16x8*)((char*)d_ws + 1024);
    unsigned* wlist = (unsigned*)((char*)d_ws + 1024 + 262144);
    size_t rem = (ws_size - 1024 - 262144) / 4;
    unsigned cap = (unsigned)(rem > (1u << 22) ? (1u << 22) : rem);

    (void)hipMemsetAsync(d_ws, 0, 64, stream);
    prep_w<<<dim3(32), dim3(256), 0, stream>>>(W, wpl);
    router_mfma<<<dim3(T_TOKENS / 128), dim3(256), 0, stream>>>(x, wpl, out, wcnt, wlist, cap);
    router_fixup<<<dim3(512), dim3(256), 0, stream>>>(x, W, out, wcnt, wlist, cap);
}